// Round 2
// baseline (507.223 us; speedup 1.0000x reference)
//
#include <hip/hip_runtime.h>
#include <hip/hip_cooperative_groups.h>

namespace cg = cooperative_groups;

#define N_PTS 4096
#define ICP_STEPS 10
#define NBLK 512          // 2 blocks/CU on 256 CUs; exactly co-resident (66 KB LDS each)
#define POWER_ITERS 32

// One fused cooperative kernel: stages p2 once into LDS, runs all 10 ICP steps
// with one grid.sync() per step, keeps each wave's 2 owned query points in
// registers for the whole kernel, accumulates the composed transform, and
// writes [R|t] at the end (final Kabsch(p1,pc) == composition, exactly).
__global__ __launch_bounds__(256, 2) void icp_fused(const float* __restrict__ p1,
                                                    const float* __restrict__ p2,
                                                    float* __restrict__ partials,  // [2][NBLK][16]
                                                    float* __restrict__ out) {
    cg::grid_group grid = cg::this_grid();

    __shared__ __align__(16) float4 sp2[N_PTS];   // 64 KB: {x,y,z,|p|^2}
    __shared__ float wred[4][16];                 // per-wave partials
    __shared__ float rred[16][17];                // reduce scratch (+1 pad)

    const int tid = threadIdx.x;
    const int bid = blockIdx.x;
    const int wave = tid >> 6;
    const int lane = tid & 63;

    // ---- stage p2 -> LDS once, with precomputed squared norm ----
    for (int p = tid; p < N_PTS; p += 256) {
        const float x = p2[3 * p + 0];
        const float y = p2[3 * p + 1];
        const float z = p2[3 * p + 2];
        sp2[p] = make_float4(x, y, z, x * x + y * y + z * z);
    }

    // ---- owned queries: block owns 8 points, wave owns 2 (in registers) ----
    const int q0 = bid * 8 + wave * 2;
    const int q1 = q0 + 1;
    float q0x = p1[3 * q0 + 0], q0y = p1[3 * q0 + 1], q0z = p1[3 * q0 + 2];
    float q1x = p1[3 * q1 + 0], q1y = p1[3 * q1 + 1], q1z = p1[3 * q1 + 2];

    // accumulated transform (tracked redundantly by every thread)
    float cqw = 1.0f, cqx = 0.0f, cqy = 0.0f, cqz = 0.0f;  // quaternion of R_total
    float ctx = 0.0f, cty = 0.0f, ctz = 0.0f;              // t_total

    __syncthreads();

    for (int step = 0; step < ICP_STEPS; ++step) {
        // ---- 1-NN via argmin_j (|p_j|^2 - 2 q.p_j): 3 FMA per (q, cand) ----
        const float a0x = -2.0f * q0x, a0y = -2.0f * q0y, a0z = -2.0f * q0z;
        const float a1x = -2.0f * q1x, a1y = -2.0f * q1y, a1z = -2.0f * q1z;
        float b0 = 3.4e38f, b1 = 3.4e38f;
        int i0 = 0, i1 = 0;
        #pragma unroll 8
        for (int k = 0; k < N_PTS / 64; ++k) {
            const int j = lane + (k << 6);
            const float4 P = sp2[j];
            float s0 = __builtin_fmaf(P.z, a0z, P.w);
            s0 = __builtin_fmaf(P.y, a0y, s0);
            s0 = __builtin_fmaf(P.x, a0x, s0);
            float s1 = __builtin_fmaf(P.z, a1z, P.w);
            s1 = __builtin_fmaf(P.y, a1y, s1);
            s1 = __builtin_fmaf(P.x, a1x, s1);
            if (s0 < b0) { b0 = s0; i0 = j; }   // ascending j: smallest index on tie
            if (s1 < b1) { b1 = s1; i1 = j; }
        }
        // wave-wide argmin, tie -> smaller index (matches jnp.argmin)
        for (int off = 32; off; off >>= 1) {
            const float o0 = __shfl_xor(b0, off, 64);
            const int oj0 = __shfl_xor(i0, off, 64);
            if (o0 < b0 || (o0 == b0 && oj0 < i0)) { b0 = o0; i0 = oj0; }
            const float o1 = __shfl_xor(b1, off, 64);
            const int oj1 = __shfl_xor(i1, off, 64);
            if (o1 < b1 || (o1 == b1 && oj1 < i1)) { b1 = o1; i1 = oj1; }
        }
        const float4 M0 = sp2[i0];  // uniform address -> LDS broadcast
        const float4 M1 = sp2[i1];

        // ---- per-wave Kabsch partials (S1, S2, src (x) match) ----
        __syncthreads();  // protect wred[0] reads of previous step
        if (lane == 0) {
            float* r = wred[wave];
            r[0]  = q0x + q1x;           r[1]  = q0y + q1y;           r[2]  = q0z + q1z;
            r[3]  = M0.x + M1.x;         r[4]  = M0.y + M1.y;         r[5]  = M0.z + M1.z;
            r[6]  = q0x * M0.x + q1x * M1.x;
            r[7]  = q0x * M0.y + q1x * M1.y;
            r[8]  = q0x * M0.z + q1x * M1.z;
            r[9]  = q0y * M0.x + q1y * M1.x;
            r[10] = q0y * M0.y + q1y * M1.y;
            r[11] = q0y * M0.z + q1y * M1.z;
            r[12] = q0z * M0.x + q1z * M1.x;
            r[13] = q0z * M0.y + q1z * M1.y;
            r[14] = q0z * M0.z + q1z * M1.z;
            r[15] = 0.0f;
        }
        __syncthreads();
        float* prow = partials + ((size_t)(step & 1) * NBLK + bid) * 16;
        if (tid < 16) {
            prow[tid] = wred[0][tid] + wred[1][tid] + wred[2][tid] + wred[3][tid];
        }

        grid.sync();

        // ---- every block reduces all NBLK partial rows (coalesced L2 reads) ----
        {
            const int v = tid & 15;        // which of the 16 values
            const int g = tid >> 4;        // row group 0..15
            const float* base = partials + (size_t)(step & 1) * NBLK * 16;
            float s = 0.0f;
            #pragma unroll 8
            for (int r = g; r < NBLK; r += 16) s += base[r * 16 + v];
            rred[v][g] = s;
        }
        __syncthreads();
        if (tid < 16) {
            float s = 0.0f;
            #pragma unroll
            for (int g = 0; g < 16; ++g) s += rred[tid][g];
            wred[0][tid] = s;
        }
        __syncthreads();

        const float S1x = wred[0][0], S1y = wred[0][1], S1z = wred[0][2];
        const float S2x = wred[0][3], S2y = wred[0][4], S2z = wred[0][5];
        const float Mxx = wred[0][6], Mxy = wred[0][7], Mxz = wred[0][8];
        const float Myx = wred[0][9], Myy = wred[0][10], Myz = wred[0][11];
        const float Mzx = wred[0][12], Mzy = wred[0][13], Mzz = wred[0][14];

        const float invN = 1.0f / (float)N_PTS;
        const float c1x = S1x * invN, c1y = S1y * invN, c1z = S1z * invN;
        const float c2x = S2x * invN, c2y = S2y * invN, c2z = S2z * invN;

        const float Sxx = Mxx - S1x * S2x * invN;
        const float Sxy = Mxy - S1x * S2y * invN;
        const float Sxz = Mxz - S1x * S2z * invN;
        const float Syx = Myx - S1y * S2x * invN;
        const float Syy = Myy - S1y * S2y * invN;
        const float Syz = Myz - S1y * S2z * invN;
        const float Szx = Mzx - S1z * S2x * invN;
        const float Szy = Mzy - S1z * S2y * invN;
        const float Szz = Mzz - S1z * S2z * invN;

        // Horn's 4x4 N matrix, shifted power iteration for max eigenvector
        const float N00 = Sxx + Syy + Szz;
        const float N01 = Syz - Szy;
        const float N02 = Szx - Sxz;
        const float N03 = Sxy - Syx;
        const float N11 = Sxx - Syy - Szz;
        const float N12 = Sxy + Syx;
        const float N13 = Szx + Sxz;
        const float N22 = -Sxx + Syy - Szz;
        const float N23 = Syz + Szy;
        const float N33 = -Sxx - Syy + Szz;

        const float fro = sqrtf(N00 * N00 + N11 * N11 + N22 * N22 + N33 * N33 +
                                2.0f * (N01 * N01 + N02 * N02 + N03 * N03 +
                                        N12 * N12 + N13 * N13 + N23 * N23));
        const float sg = fro + 1e-20f;

        float w = 1.0f, x = 0.0f, y = 0.0f, z = 0.0f;
        for (int it = 0; it < POWER_ITERS; ++it) {
            const float r0 = N00 * w + N01 * x + N02 * y + N03 * z + sg * w;
            const float r1 = N01 * w + N11 * x + N12 * y + N13 * z + sg * x;
            const float r2 = N02 * w + N12 * x + N22 * y + N23 * z + sg * y;
            const float r3 = N03 * w + N13 * x + N23 * y + N33 * z + sg * z;
            const float inv = rsqrtf(r0 * r0 + r1 * r1 + r2 * r2 + r3 * r3 + 1e-30f);
            w = r0 * inv; x = r1 * inv; y = r2 * inv; z = r3 * inv;
        }

        const float xx = x * x, yy = y * y, zz = z * z;
        const float xy = x * y, xz = x * z, yz = y * z;
        const float wx = w * x, wy = w * y, wz = w * z;
        const float R00 = 1.0f - 2.0f * (yy + zz), R01 = 2.0f * (xy - wz), R02 = 2.0f * (xz + wy);
        const float R10 = 2.0f * (xy + wz), R11 = 1.0f - 2.0f * (xx + zz), R12 = 2.0f * (yz - wx);
        const float R20 = 2.0f * (xz - wy), R21 = 2.0f * (yz + wx), R22 = 1.0f - 2.0f * (xx + yy);

        const float tx = c2x - (R00 * c1x + R01 * c1y + R02 * c1z);
        const float ty = c2y - (R10 * c1x + R11 * c1y + R12 * c1z);
        const float tz = c2z - (R20 * c1x + R21 * c1y + R22 * c1z);

        // ---- transform owned queries (registers only) ----
        {
            const float nx0 = R00 * q0x + R01 * q0y + R02 * q0z + tx;
            const float ny0 = R10 * q0x + R11 * q0y + R12 * q0z + ty;
            const float nz0 = R20 * q0x + R21 * q0y + R22 * q0z + tz;
            const float nx1 = R00 * q1x + R01 * q1y + R02 * q1z + tx;
            const float ny1 = R10 * q1x + R11 * q1y + R12 * q1z + ty;
            const float nz1 = R20 * q1x + R21 * q1y + R22 * q1z + tz;
            q0x = nx0; q0y = ny0; q0z = nz0;
            q1x = nx1; q1y = ny1; q1z = nz1;
        }

        // ---- compose totals: q_tot = q_step (*) q_tot ; t_tot = R_step t_tot + t_step ----
        {
            const float nw = w * cqw - x * cqx - y * cqy - z * cqz;
            const float nx = w * cqx + x * cqw + y * cqz - z * cqy;
            const float ny = w * cqy - x * cqz + y * cqw + z * cqx;
            const float nz = w * cqz + x * cqy - y * cqx + z * cqw;
            cqw = nw; cqx = nx; cqy = ny; cqz = nz;
            const float ntx = R00 * ctx + R01 * cty + R02 * ctz + tx;
            const float nty = R10 * ctx + R11 * cty + R12 * ctz + ty;
            const float ntz = R20 * ctx + R21 * cty + R22 * ctz + tz;
            ctx = ntx; cty = nty; ctz = ntz;
        }
    }

    // ---- final Kabsch(p1, pc) == composed transform (exact; H = C*Rc^T, C SPD) ----
    if (bid == 0 && tid == 0) {
        const float xx = cqx * cqx, yy = cqy * cqy, zz = cqz * cqz;
        const float xy = cqx * cqy, xz = cqx * cqz, yz = cqy * cqz;
        const float wx = cqw * cqx, wy = cqw * cqy, wz = cqw * cqz;
        out[0]  = 1.0f - 2.0f * (yy + zz);
        out[1]  = 2.0f * (xy - wz);
        out[2]  = 2.0f * (xz + wy);
        out[3]  = ctx;
        out[4]  = 2.0f * (xy + wz);
        out[5]  = 1.0f - 2.0f * (xx + zz);
        out[6]  = 2.0f * (yz - wx);
        out[7]  = cty;
        out[8]  = 2.0f * (xz - wy);
        out[9]  = 2.0f * (yz + wx);
        out[10] = 1.0f - 2.0f * (xx + yy);
        out[11] = ctz;
    }
}

extern "C" void kernel_launch(void* const* d_in, const int* in_sizes, int n_in,
                              void* d_out, int out_size, void* d_ws, size_t ws_size,
                              hipStream_t stream) {
    const float* p1 = (const float*)d_in[0];
    const float* p2 = (const float*)d_in[1];
    float* out = (float*)d_out;
    float* partials = (float*)d_ws;  // 2 * NBLK * 16 floats = 64 KB

    void* args[] = {(void*)&p1, (void*)&p2, (void*)&partials, (void*)&out};
    hipLaunchCooperativeKernel((const void*)icp_fused, dim3(NBLK), dim3(256),
                               args, 0, stream);
}